// Round 1
// baseline (506.678 us; speedup 1.0000x reference)
//
#include <hip/hip_runtime.h>
#include <math.h>

#define BB 64
#define NN 4096
#define FF 128
#define DD 129
#define EPSL 1e-7f

// ws layout (floats):
// [0, 8256)        s_sum[64][129]   (atomic, zeroed each call)
// [8256, 8320)     var_sum[64]      (atomic, zeroed each call)
// [8320, 16576)    mu[64][129]
// [16576, 16705)   bias_m[129]
// [16705, 16769)   denom[64]
// [16769, 16833)   scale[64]
#define WS_SSUM   0
#define WS_VSUM   8256
#define WS_MU     8320
#define WS_BM     16576
#define WS_DENOM  16705
#define WS_SCALE  16769

__device__ __forceinline__ float wave_sum(float p) {
    p += __shfl_xor(p, 1);
    p += __shfl_xor(p, 2);
    p += __shfl_xor(p, 4);
    p += __shfl_xor(p, 8);
    p += __shfl_xor(p, 16);
    p += __shfl_xor(p, 32);
    return p;
}

// ---- Kernel 1: per-batch component sum ----
__global__ __launch_bounds__(256) void k_sum(const float* __restrict__ x,
                                             float* __restrict__ ws) {
    const int CH = 16;                 // chunks per batch
    int blk = blockIdx.x;
    int b = blk / CH, chunk = blk % CH;
    int tid = threadIdx.x, w = tid >> 6, l = tid & 63;
    const float* xb = x + (size_t)b * NN * DD;
    int r0 = chunk * (NN / CH) + w * 64;   // 64 rows per wave
    float a0 = 0.f, a1 = 0.f, a2 = 0.f;
    for (int i = 0; i < 64; ++i) {
        const float* row = xb + (size_t)(r0 + i) * DD;
        a0 += row[l];
        a1 += row[64 + l];
        if (l == 0) a2 += row[128];
    }
    __shared__ float part[4][DD];
    part[w][l] = a0;
    part[w][64 + l] = a1;
    if (l == 0) part[w][128] = a2;
    __syncthreads();
    if (tid < DD) {
        float s = part[0][tid] + part[1][tid] + part[2][tid] + part[3][tid];
        atomicAdd(&ws[WS_SSUM + b * DD + tid], s);
    }
}

// ---- Kernel 2: mu per batch (blocks 1..64) + bias_m (block 0) ----
__global__ __launch_bounds__(256) void k_mu(const float* __restrict__ bias,
                                            float* __restrict__ ws) {
    __shared__ float red[256];
    int tid = threadIdx.x;
    if (blockIdx.x == 0) {
        float v = (tid < FF) ? bias[tid] : 0.f;
        red[tid] = v * v;
        __syncthreads();
        for (int st = 128; st > 0; st >>= 1) {
            if (tid < st) red[tid] += red[tid + st];
            __syncthreads();
        }
        float n = sqrtf(fmaxf(red[0], EPSL));
        float sh = sinhf(n) / n;
        if (tid == 0) ws[WS_BM + 0] = coshf(n);
        if (tid < FF) ws[WS_BM + 1 + tid] = sh * bias[tid];
    } else {
        int b = blockIdx.x - 1;
        const float* s = ws + WS_SSUM + b * DD;
        float v = (tid < DD) ? s[tid] : 0.f;
        float sgn = (tid == 0) ? -1.f : 1.f;
        red[tid] = sgn * v * v;            // accumulates ldot(s,s)
        __syncthreads();
        for (int st = 128; st > 0; st >>= 1) {
            if (tid < st) red[tid] += red[tid + st];
            __syncthreads();
        }
        float q = fmaxf(-red[0], EPSL);    // -ldot(s,s)
        float inv = 1.f / sqrtf(q);
        if (tid < DD) ws[WS_MU + b * DD + tid] = v * inv;
    }
}

// ---- Kernel 3: Frechet variance partials ----
__global__ __launch_bounds__(256) void k_var(const float* __restrict__ x,
                                             float* __restrict__ ws) {
    const int CH = 16;
    int blk = blockIdx.x;
    int b = blk / CH, chunk = blk % CH;
    int tid = threadIdx.x, w = tid >> 6, l = tid & 63;
    const float* mu = ws + WS_MU + b * DD;
    float m0 = mu[l], m1 = mu[64 + l], m2 = (l == 0) ? mu[128] : 0.f;
    const float* xb = x + (size_t)b * NN * DD;
    int r0 = chunk * (NN / CH) + w * 64;
    float acc = 0.f;
    for (int i = 0; i < 64; ++i) {
        const float* row = xb + (size_t)(r0 + i) * DD;
        float x0 = row[l], x1 = row[64 + l];
        float x2 = (l == 0) ? row[128] : 0.f;
        float p = ((l == 0) ? -m0 * x0 : m0 * x0) + m1 * x1 + m2 * x2;
        p = wave_sum(p);                    // = ldot(mu, x)
        float alpha = fmaxf(-p, 1.f + EPSL);
        float d = acoshf(alpha);
        acc += d * d;
    }
    if (l == 0) atomicAdd(&ws[WS_VSUM + b], acc);
}

// ---- Kernel 4: denom + scale per batch ----
__global__ __launch_bounds__(256) void k_fin(const float* __restrict__ weight,
                                             float* __restrict__ ws) {
    int b = blockIdx.x;
    int tid = threadIdx.x;
    __shared__ float red[256];
    const float* mu = ws + WS_MU + b * DD;
    const float* bm = ws + WS_BM;
    float v = 0.f;
    if (tid < DD) v = ((tid == 0) ? -1.f : 1.f) * mu[tid] * bm[tid];
    red[tid] = v;
    __syncthreads();
    for (int st = 128; st > 0; st >>= 1) {
        if (tid < st) red[tid] += red[tid + st];
        __syncthreads();
    }
    if (tid == 0) {
        ws[WS_DENOM + b] = 1.f - red[0];            // 1 - ldot(mu, bias_m)
        float var = ws[WS_VSUM + b] / (float)NN;
        ws[WS_SCALE + b] = sqrtf(weight[0] / (var + 1e-6f));
    }
}

// ---- Kernel 5: pointwise logmap -> transport -> scale -> expmap ----
__global__ __launch_bounds__(256) void k_out(const float* __restrict__ x,
                                             float* __restrict__ out,
                                             const float* __restrict__ ws) {
    int blk = blockIdx.x;
    int b = blk >> 6;                 // 64 chunks per batch
    int chunk = blk & 63;
    int tid = threadIdx.x, w = tid >> 6, l = tid & 63;
    const float* mu = ws + WS_MU + b * DD;
    const float* bm = ws + WS_BM;
    float denom = ws[WS_DENOM + b];
    float scale = ws[WS_SCALE + b];
    float m0 = mu[l], m1 = mu[64 + l], m2 = (l == 0) ? mu[128] : 0.f;
    float b0 = bm[l], b1 = bm[64 + l], b2 = (l == 0) ? bm[128] : 0.f;
    float p0 = m0 + b0, p1 = m1 + b1, p2 = m2 + b2;
    const float* xb = x + (size_t)b * NN * DD;
    float* ob = out + (size_t)b * NN * DD;
    int r0 = chunk * 64 + w * 16;     // 16 rows per wave
    for (int i = 0; i < 16; ++i) {
        int r = r0 + i;
        const float* row = xb + (size_t)r * DD;
        float x0 = row[l], x1 = row[64 + l];
        float x2 = (l == 0) ? row[128] : 0.f;
        // alpha = max(-ldot(mu,x), 1+eps)
        float p = ((l == 0) ? -m0 * x0 : m0 * x0) + m1 * x1 + m2 * x2;
        p = wave_sum(p);
        float alpha = fmaxf(-p, 1.f + EPSL);
        float d = acoshf(alpha);
        // u = x - alpha*mu
        float u0 = x0 - alpha * m0, u1 = x1 - alpha * m1, u2 = x2 - alpha * m2;
        float q = ((l == 0) ? -u0 * u0 : u0 * u0) + u1 * u1 + u2 * u2;
        q = wave_sum(q);                       // ldot(u,u)
        float g = ((l == 0) ? -b0 * u0 : b0 * u0) + b1 * u1 + b2 * u2;
        g = wave_sum(g);                       // ldot(bias_m, u)
        float nu = sqrtf(fmaxf(q, EPSL));
        float f = d / nu;                      // v = f*u
        float ct = f * g / denom;              // ldot(bias_m,v)/denom
        // vt = scale * (v + ct*(mu+bias_m))
        float vt0 = scale * (f * u0 + ct * p0);
        float vt1 = scale * (f * u1 + ct * p1);
        float vt2 = scale * (f * u2 + ct * p2);
        float vv = ((l == 0) ? -vt0 * vt0 : vt0 * vt0) + vt1 * vt1 + vt2 * vt2;
        vv = wave_sum(vv);                     // ldot(vt,vt)
        float nn = sqrtf(fmaxf(vv, EPSL));
        float ch = coshf(nn);
        float sh = sinhf(nn) / nn;
        float* orow = ob + (size_t)r * DD;
        orow[l] = ch * b0 + sh * vt0;
        orow[64 + l] = ch * b1 + sh * vt1;
        if (l == 0) orow[128] = ch * b2 + sh * vt2;
    }
}

extern "C" void kernel_launch(void* const* d_in, const int* in_sizes, int n_in,
                              void* d_out, int out_size, void* d_ws, size_t ws_size,
                              hipStream_t stream) {
    const float* x = (const float*)d_in[0];
    const float* bias = (const float*)d_in[1];
    const float* weight = (const float*)d_in[2];
    float* out = (float*)d_out;
    float* ws = (float*)d_ws;

    // zero the atomic accumulators (s_sum + var_sum)
    hipMemsetAsync(ws, 0, (size_t)(8256 + 64) * sizeof(float), stream);

    k_sum<<<dim3(BB * 16), dim3(256), 0, stream>>>(x, ws);
    k_mu<<<dim3(BB + 1), dim3(256), 0, stream>>>(bias, ws);
    k_var<<<dim3(BB * 16), dim3(256), 0, stream>>>(x, ws);
    k_fin<<<dim3(BB), dim3(256), 0, stream>>>(weight, ws);
    k_out<<<dim3(BB * 64), dim3(256), 0, stream>>>(x, out, ws);
}

// Round 2
// 353.292 us; speedup vs baseline: 1.4342x; 1.4342x over previous
//
#include <hip/hip_runtime.h>
#include <math.h>

#define BB 64
#define NN 4096
#define FF 128
#define DD 129
#define EPSL 1e-7f
#define ROWS (BB * NN)

// ws layout (float offsets)
#define WS_SSUM   0          // [64][129] atomic, zeroed
#define WS_VSUM   8256       // [64]      atomic, zeroed
#define WS_MU     8320       // [64][129]
#define WS_BM     16576      // [129]
#define WS_CMB    16705      // [64]  ldot(mu_b, bm)
#define WS_DENOM  16769      // [64]  1 - cmb
#define WS_SCALE  16833      // [64]  sqrt(w/(var+1e-6))
#define WS_PG     16900      // [ROWS][2] (p, g0) pairs
#define WS_SPLIT_FLOATS (WS_PG + 2 * ROWS)

__device__ __forceinline__ float wave_sum(float p) {
    p += __shfl_xor(p, 1);
    p += __shfl_xor(p, 2);
    p += __shfl_xor(p, 4);
    p += __shfl_xor(p, 8);
    p += __shfl_xor(p, 16);
    p += __shfl_xor(p, 32);
    return p;
}

// ---- Kernel 1: per-batch component sums ----
__global__ __launch_bounds__(256) void k_sum(const float* __restrict__ x,
                                             float* __restrict__ ws) {
    const int CH = 16;
    int b = blockIdx.x / CH, chunk = blockIdx.x % CH;
    int tid = threadIdx.x, w = tid >> 6, l = tid & 63;
    const float* xb = x + (size_t)b * NN * DD;
    int r0 = chunk * (NN / CH) + w * 64;
    float a0 = 0.f, a1 = 0.f, a2 = 0.f;
    for (int i = 0; i < 64; ++i) {
        const float* row = xb + (size_t)(r0 + i) * DD;
        a0 += row[l];
        a1 += row[64 + l];
        if (l == 0) a2 += row[128];
    }
    __shared__ float part[4][DD];
    part[w][l] = a0;
    part[w][64 + l] = a1;
    if (l == 0) part[w][128] = a2;
    __syncthreads();
    if (tid < DD) {
        float s = part[0][tid] + part[1][tid] + part[2][tid] + part[3][tid];
        atomicAdd(&ws[WS_SSUM + b * DD + tid], s);
    }
}

// ---- Kernel 2: mu per batch (blocks 1..64) + bias_m (block 0) ----
__global__ __launch_bounds__(256) void k_mu(const float* __restrict__ bias,
                                            float* __restrict__ ws) {
    __shared__ float red[256];
    int tid = threadIdx.x;
    if (blockIdx.x == 0) {
        float v = (tid < FF) ? bias[tid] : 0.f;
        red[tid] = v * v;
        __syncthreads();
        for (int st = 128; st > 0; st >>= 1) {
            if (tid < st) red[tid] += red[tid + st];
            __syncthreads();
        }
        float n = sqrtf(fmaxf(red[0], EPSL));
        float sh = sinhf(n) / n;
        if (tid == 0) ws[WS_BM + 0] = coshf(n);
        if (tid < FF) ws[WS_BM + 1 + tid] = sh * bias[tid];
    } else {
        int b = blockIdx.x - 1;
        const float* s = ws + WS_SSUM + b * DD;
        float v = (tid < DD) ? s[tid] : 0.f;
        float sgn = (tid == 0) ? -1.f : 1.f;
        red[tid] = sgn * v * v;
        __syncthreads();
        for (int st = 128; st > 0; st >>= 1) {
            if (tid < st) red[tid] += red[tid + st];
            __syncthreads();
        }
        float q = fmaxf(-red[0], EPSL);
        float inv = 1.f / sqrtf(q);
        if (tid < DD) ws[WS_MU + b * DD + tid] = v * inv;
    }
}

// ---- Kernel 3: per-row dots p=ldot(mu,x), g0=ldot(bm,x); var accumulation ----
__global__ __launch_bounds__(256) void k_dots(const float* __restrict__ x,
                                              float* __restrict__ ws,
                                              float* __restrict__ pg) {
    const int CH = 16;
    int b = blockIdx.x / CH, chunk = blockIdx.x % CH;
    int tid = threadIdx.x, w = tid >> 6, l = tid & 63;
    const float* mu = ws + WS_MU + b * DD;
    const float* bm = ws + WS_BM;
    float m0 = mu[l], m1 = mu[64 + l], m2 = (l == 0) ? mu[128] : 0.f;
    float b0 = bm[l], b1 = bm[64 + l], b2 = (l == 0) ? bm[128] : 0.f;
    if (l == 0) { m0 = -m0; b0 = -b0; }   // Minkowski sign folded into lane-0 copy
    const float* xb = x + (size_t)b * NN * DD;
    int r0 = chunk * (NN / CH) + w * 64;
    float acc = 0.f;
    for (int i = 0; i < 64; ++i) {
        int r = r0 + i;
        const float* row = xb + (size_t)r * DD;
        float x0 = row[l], x1 = row[64 + l];
        float x2 = (l == 0) ? row[128] : 0.f;
        float p = m0 * x0 + m1 * x1 + m2 * x2;
        float g = b0 * x0 + b1 * x1 + b2 * x2;
        p += __shfl_xor(p, 1);  g += __shfl_xor(g, 1);
        p += __shfl_xor(p, 2);  g += __shfl_xor(g, 2);
        p += __shfl_xor(p, 4);  g += __shfl_xor(g, 4);
        p += __shfl_xor(p, 8);  g += __shfl_xor(g, 8);
        p += __shfl_xor(p, 16); g += __shfl_xor(g, 16);
        p += __shfl_xor(p, 32); g += __shfl_xor(g, 32);
        float alpha = fmaxf(-p, 1.f + EPSL);
        float nuu = fmaxf(alpha * alpha - 1.f, EPSL);
        float nu = sqrtf(nuu);
        float d = __logf(alpha + nu);        // acosh(alpha)
        acc += d * d;
        if (pg != nullptr && l == 0) {
            float2 v; v.x = p; v.y = g;
            ((float2*)pg)[(size_t)b * NN + r] = v;
        }
    }
    __shared__ float part[4];
    if (l == 0) part[w] = acc;
    __syncthreads();
    if (tid == 0) atomicAdd(&ws[WS_VSUM + b], part[0] + part[1] + part[2] + part[3]);
}

// ---- Kernel 4: cmb, denom, scale per batch ----
__global__ __launch_bounds__(256) void k_fin(const float* __restrict__ weight,
                                             float* __restrict__ ws) {
    int b = blockIdx.x;
    int tid = threadIdx.x;
    __shared__ float red[256];
    const float* mu = ws + WS_MU + b * DD;
    const float* bm = ws + WS_BM;
    float v = 0.f;
    if (tid < DD) v = ((tid == 0) ? -1.f : 1.f) * mu[tid] * bm[tid];
    red[tid] = v;
    __syncthreads();
    for (int st = 128; st > 0; st >>= 1) {
        if (tid < st) red[tid] += red[tid + st];
        __syncthreads();
    }
    if (tid == 0) {
        float cmb = red[0];
        ws[WS_CMB + b] = cmb;
        ws[WS_DENOM + b] = 1.f - cmb;
        float var = ws[WS_VSUM + b] * (1.f / (float)NN);
        ws[WS_SCALE + b] = sqrtf(weight[0] / (var + 1e-6f));
    }
}

// per-row coefficient math from (p, g0) + batch scalars
__device__ __forceinline__ void row_coeffs(float p, float g0, float cmb,
                                           float denom, float scale,
                                           float& A, float& Bc, float& Cc) {
    float alpha = fmaxf(-p, 1.f + EPSL);
    float nuu = fmaxf(alpha * alpha - 1.f, EPSL);   // ldot(u,u)
    float nu = sqrtf(nuu);
    float d = __logf(alpha + nu);                   // acosh(alpha)
    float f = d / nu;                               // v = f*u
    float g = g0 - alpha * cmb;                     // ldot(bm, u)
    float ct = f * g / denom;
    // ldot(vt,vt) = scale^2 (f^2 nuu + 2 f ct ldot(u,mu+bm) + ct^2 ldot(mu+bm,mu+bm))
    //   ldot(u,mu)=p+alpha ; ldot(u,bm)=g ; ldot(mu+bm,mu+bm) = -2*denom
    float nn2 = scale * scale * (f * f * nuu + 2.f * f * ct * (p + alpha + g)
                                 - 2.f * ct * ct * denom);
    float nn = sqrtf(fmaxf(nn2, EPSL));
    float e = __expf(nn), ei = __expf(-nn);
    float ch = 0.5f * (e + ei);
    float shn = 0.5f * (e - ei) / nn;               // sinh(nn)/nn
    float sf = shn * scale;
    A = sf * f;                                     // out = A*x + Bc*mu + Cc*bm
    Bc = sf * (ct - f * alpha);
    Cc = ch + sf * ct;
}

// ---- Kernel 5 (split path): coefficients once per row, then streaming combine ----
__global__ __launch_bounds__(256) void k_out2(const float* __restrict__ x,
                                              const float* __restrict__ pg,
                                              float* __restrict__ out,
                                              const float* __restrict__ ws) {
    int blk = blockIdx.x;             // 64 batches * 64 tiles
    int b = blk >> 6, tile = blk & 63;
    int tid = threadIdx.x, w = tid >> 6, l = tid & 63;
    int rbase = tile * 64;
    __shared__ float As[64], Bs[64], Cs[64];
    if (tid < 64) {
        float2 v = ((const float2*)pg)[(size_t)b * NN + rbase + tid];
        float A, Bc, Cc;
        row_coeffs(v.x, v.y, ws[WS_CMB + b], ws[WS_DENOM + b], ws[WS_SCALE + b],
                   A, Bc, Cc);
        As[tid] = A; Bs[tid] = Bc; Cs[tid] = Cc;
    }
    __syncthreads();
    const float* mu = ws + WS_MU + b * DD;
    const float* bm = ws + WS_BM;
    float m0 = mu[l], m1 = mu[64 + l], m2 = (l == 0) ? mu[128] : 0.f;
    float b0 = bm[l], b1 = bm[64 + l], b2 = (l == 0) ? bm[128] : 0.f;
    const float* xb = x + (size_t)b * NN * DD;
    float* ob = out + (size_t)b * NN * DD;
    for (int i = 0; i < 16; ++i) {
        int li = w * 16 + i;
        int r = rbase + li;
        const float* row = xb + (size_t)r * DD;
        float* orow = ob + (size_t)r * DD;
        float A = As[li], Bc = Bs[li], Cc = Cs[li];
        orow[l]      = A * row[l]      + Bc * m0 + Cc * b0;
        orow[64 + l] = A * row[64 + l] + Bc * m1 + Cc * b1;
        if (l == 0) orow[128] = A * row[128] + Bc * m2 + Cc * b2;
    }
}

// ---- Kernel 5 (fallback, small ws): fused butterflies + fast coeff math ----
__global__ __launch_bounds__(256) void k_out_fused(const float* __restrict__ x,
                                                   float* __restrict__ out,
                                                   const float* __restrict__ ws) {
    int blk = blockIdx.x;
    int b = blk >> 6, chunk = blk & 63;
    int tid = threadIdx.x, w = tid >> 6, l = tid & 63;
    const float* mu = ws + WS_MU + b * DD;
    const float* bm = ws + WS_BM;
    float cmb = ws[WS_CMB + b], denom = ws[WS_DENOM + b], scale = ws[WS_SCALE + b];
    float m0 = mu[l], m1 = mu[64 + l], m2 = (l == 0) ? mu[128] : 0.f;
    float b0 = bm[l], b1 = bm[64 + l], b2 = (l == 0) ? bm[128] : 0.f;
    float m0n = (l == 0) ? -m0 : m0;
    float b0n = (l == 0) ? -b0 : b0;
    const float* xb = x + (size_t)b * NN * DD;
    float* ob = out + (size_t)b * NN * DD;
    int r0 = chunk * 64 + w * 16;
    for (int i = 0; i < 16; ++i) {
        int r = r0 + i;
        const float* row = xb + (size_t)r * DD;
        float x0 = row[l], x1 = row[64 + l];
        float x2 = (l == 0) ? row[128] : 0.f;
        float p = m0n * x0 + m1 * x1 + m2 * x2;
        float g = b0n * x0 + b1 * x1 + b2 * x2;
        p += __shfl_xor(p, 1);  g += __shfl_xor(g, 1);
        p += __shfl_xor(p, 2);  g += __shfl_xor(g, 2);
        p += __shfl_xor(p, 4);  g += __shfl_xor(g, 4);
        p += __shfl_xor(p, 8);  g += __shfl_xor(g, 8);
        p += __shfl_xor(p, 16); g += __shfl_xor(g, 16);
        p += __shfl_xor(p, 32); g += __shfl_xor(g, 32);
        float A, Bc, Cc;
        row_coeffs(p, g, cmb, denom, scale, A, Bc, Cc);
        float* orow = ob + (size_t)r * DD;
        orow[l]      = A * x0 + Bc * m0 + Cc * b0;
        orow[64 + l] = A * x1 + Bc * m1 + Cc * b1;
        if (l == 0) orow[128] = A * x2 + Bc * m2 + Cc * b2;
    }
}

extern "C" void kernel_launch(void* const* d_in, const int* in_sizes, int n_in,
                              void* d_out, int out_size, void* d_ws, size_t ws_size,
                              hipStream_t stream) {
    const float* x = (const float*)d_in[0];
    const float* bias = (const float*)d_in[1];
    const float* weight = (const float*)d_in[2];
    float* out = (float*)d_out;
    float* ws = (float*)d_ws;

    bool split = ws_size >= (size_t)WS_SPLIT_FLOATS * sizeof(float);

    // zero atomic accumulators (s_sum + var_sum)
    hipMemsetAsync(ws, 0, (size_t)(8256 + 64) * sizeof(float), stream);

    k_sum<<<dim3(BB * 16), dim3(256), 0, stream>>>(x, ws);
    k_mu<<<dim3(BB + 1), dim3(256), 0, stream>>>(bias, ws);
    k_dots<<<dim3(BB * 16), dim3(256), 0, stream>>>(x, ws, split ? ws + WS_PG : nullptr);
    k_fin<<<dim3(BB), dim3(256), 0, stream>>>(weight, ws);
    if (split) {
        k_out2<<<dim3(BB * 64), dim3(256), 0, stream>>>(x, ws + WS_PG, out, ws);
    } else {
        k_out_fused<<<dim3(BB * 64), dim3(256), 0, stream>>>(x, out, ws);
    }
}